// Round 1
// baseline (740.619 us; speedup 1.0000x reference)
//
#include <hip/hip_runtime.h>
#include <hip/hip_bf16.h>

constexpr int TSEQ  = 2048;
constexpr int HDIM  = 1024;
constexpr int BATCH = 32;
constexpr int BM = 128, BN = 128, BK = 64;
constexpr int KTOT = 2 * HDIM;   // query||key along K
constexpr int NT   = KTOT / BK;  // 32 K-steps
constexpr int NPART = 16;        // 8 n-blocks * 2 wave-cols partial slots per row

typedef __attribute__((ext_vector_type(8))) short bf16x8;
typedef __attribute__((ext_vector_type(4))) float f32x4;

__device__ __forceinline__ unsigned short f2bf(float f) {
    union { float f; unsigned int u; } v; v.f = f;
    unsigned int r = v.u + 0x7FFFu + ((v.u >> 16) & 1u);  // RTNE
    return (unsigned short)(r >> 16);
}

// Fused GEMM: s = [query||key] @ [Wq||Wk]^T + (bq+bk); epilogue tanh*Wz partial row-sums.
// scorePartial[r*16 + nb*2 + wc] = sum over this block/wave-col's 64 columns.
__global__ __launch_bounds__(256, 2)
void score_gemm(const float* __restrict__ query, const float* __restrict__ key_,
                const float* __restrict__ Wq, const float* __restrict__ Wk,
                const float* __restrict__ bq, const float* __restrict__ bk,
                const float* __restrict__ Wz,
                float* __restrict__ scorePartial) {
    __shared__ unsigned short As[2][BM * BK];   // [row][k] bf16, row stride 128B, XOR-swizzled
    __shared__ unsigned short Bs[2][BN * BK];

    const int tid  = threadIdx.x;
    const int lane = tid & 63;
    const int wid  = tid >> 6;
    const int wr   = wid >> 1, wc = wid & 1;

    const int bid = blockIdx.x;
    const int nb  = bid & 7;          // N-block (inner -> spreads across XCDs, B panel L2-resident)
    const int mb  = bid >> 3;
    const long rowBase = (long)mb * BM;
    const int  colBase = nb * BN;

    // staging: idx = i*256+tid -> row = i*16 + (tid>>4), float4 chunk c = tid&15
    const int srow = tid >> 4;
    const int sc   = tid & 15;

    // fragment read geometry
    const int rA  = wr * 64 + (lane & 15);
    const int rB  = wc * 64 + (lane & 15);
    const int swz = (lane & 7) << 4;        // == ((row&7)<<4) for our rows
    const int kb  = (lane >> 4) << 4;       // byte offset of lane's 8 bf16 within k-half

    f32x4 acc[4][4];
#pragma unroll
    for (int i = 0; i < 4; i++)
#pragma unroll
        for (int j = 0; j < 4; j++) acc[i][j] = (f32x4){0.f, 0.f, 0.f, 0.f};

    float4 regA[8], regB[8];

    auto stage_load = [&](int kt) {
        const int kg = kt * BK;
        const float* baseA;
        const float* baseB;
        int koff;
        if (kg < HDIM) { baseA = query; baseB = Wq; koff = kg; }
        else           { baseA = key_;  baseB = Wk; koff = kg - HDIM; }
#pragma unroll
        for (int i = 0; i < 8; i++) {
            int row = i * 16 + srow;
            regA[i] = *(const float4*)(baseA + (rowBase + row) * (long)HDIM + koff + sc * 4);
            regB[i] = *(const float4*)(baseB + (long)(colBase + row) * HDIM + koff + sc * 4);
        }
    };
    auto stage_write = [&](int buf) {
#pragma unroll
        for (int i = 0; i < 8; i++) {
            int row = i * 16 + srow;
            int off = row * 128 + (((sc * 8)) ^ ((row & 7) << 4));
            ushort4 ha, hb;
            ha.x = f2bf(regA[i].x); ha.y = f2bf(regA[i].y);
            ha.z = f2bf(regA[i].z); ha.w = f2bf(regA[i].w);
            hb.x = f2bf(regB[i].x); hb.y = f2bf(regB[i].y);
            hb.z = f2bf(regB[i].z); hb.w = f2bf(regB[i].w);
            *(ushort4*)((char*)&As[buf][0] + off) = ha;
            *(ushort4*)((char*)&Bs[buf][0] + off) = hb;
        }
    };
    auto compute = [&](int buf) {
        const char* pA = (const char*)&As[buf][0];
        const char* pB = (const char*)&Bs[buf][0];
        bf16x8 a[4][2], b[4][2];
#pragma unroll
        for (int h = 0; h < 2; h++) {
#pragma unroll
            for (int mi = 0; mi < 4; mi++) {
                int off = ((rA + mi * 16) * 128 + h * 64 + kb) ^ swz;
                a[mi][h] = *(const bf16x8*)(pA + off);
            }
#pragma unroll
            for (int ni = 0; ni < 4; ni++) {
                int off = ((rB + ni * 16) * 128 + h * 64 + kb) ^ swz;
                b[ni][h] = *(const bf16x8*)(pB + off);
            }
        }
#pragma unroll
        for (int h = 0; h < 2; h++)
#pragma unroll
            for (int mi = 0; mi < 4; mi++)
#pragma unroll
                for (int ni = 0; ni < 4; ni++)
                    acc[mi][ni] = __builtin_amdgcn_mfma_f32_16x16x32_bf16(
                        a[mi][h], b[ni][h], acc[mi][ni], 0, 0, 0);
    };

    stage_load(0);
    stage_write(0);
    __syncthreads();
    int buf = 0;
    for (int kt = 1; kt < NT; ++kt) {
        stage_load(kt);        // issue next tile's global loads early
        compute(buf);          // MFMA on current buffer
        stage_write(buf ^ 1);  // waits vmcnt, writes other buffer
        __syncthreads();
        buf ^= 1;
    }
    compute(buf);

    // epilogue: p[row] = sum_cols tanh(s + bq + bk) * Wz
    float bias[4], wz[4];
#pragma unroll
    for (int ni = 0; ni < 4; ni++) {
        int o = colBase + wc * 64 + ni * 16 + (lane & 15);
        bias[ni] = bq[o] + bk[o];
        wz[ni]   = Wz[o];
    }
#pragma unroll
    for (int mi = 0; mi < 4; mi++) {
#pragma unroll
        for (int j = 0; j < 4; j++) {
            float p = 0.f;
#pragma unroll
            for (int ni = 0; ni < 4; ni++) {
                float s = acc[mi][ni][j] + bias[ni];
                p += tanhf(s) * wz[ni];
            }
#pragma unroll
            for (int off = 1; off < 16; off <<= 1) p += __shfl_xor(p, off);
            if ((lane & 15) == 0) {
                long r = rowBase + wr * 64 + mi * 16 + (lane >> 4) * 4 + j;
                scorePartial[r * NPART + nb * 2 + wc] = p;
            }
        }
    }
}

// Per-batch masked softmax over T. Also writes att_weights to d_out.
__global__ void softmax_kernel(const float* __restrict__ sp, const float* __restrict__ bzp,
                               const int* __restrict__ lengths,
                               float* __restrict__ w_out, float* __restrict__ w_ws) {
    const int b = blockIdx.x;
    const int tid = threadIdx.x;  // 256
    const int len = lengths[b];
    const float bz = bzp[0];
    float sv[8];
    float m = -3.0e38f;
#pragma unroll
    for (int i = 0; i < 8; i++) {
        int t = i * 256 + tid;
        const float4* p = (const float4*)(sp + ((long)b * TSEQ + t) * NPART);
        float4 a = p[0], c = p[1], d = p[2], e = p[3];
        float s = (a.x + a.y + a.z + a.w) + (c.x + c.y + c.z + c.w) +
                  (d.x + d.y + d.z + d.w) + (e.x + e.y + e.z + e.w) + bz;
        if (t >= len) s = -1e9f;
        sv[i] = s;
        m = fmaxf(m, s);
    }
    __shared__ float redm[4];
    __shared__ float reds[4];
    for (int off = 32; off; off >>= 1) m = fmaxf(m, __shfl_xor(m, off));
    if ((tid & 63) == 0) redm[tid >> 6] = m;
    __syncthreads();
    m = fmaxf(fmaxf(redm[0], redm[1]), fmaxf(redm[2], redm[3]));
    float sum = 0.f;
    float ev[8];
#pragma unroll
    for (int i = 0; i < 8; i++) {
        ev[i] = expf(sv[i] - m);
        sum += ev[i];
    }
    for (int off = 32; off; off >>= 1) sum += __shfl_xor(sum, off);
    if ((tid & 63) == 0) reds[tid >> 6] = sum;
    __syncthreads();
    sum = reds[0] + reds[1] + reds[2] + reds[3];
    const float inv = 1.0f / sum;
#pragma unroll
    for (int i = 0; i < 8; i++) {
        int t = i * 256 + tid;
        float w = ev[i] * inv;
        w_out[(long)b * TSEQ + t] = w;
        w_ws[(long)b * TSEQ + t] = w;
    }
}

// att_value partial: each block does a (b, t-chunk of 128, h-chunk of 512) slab.
__global__ void pv_partial(const float* __restrict__ w, const float* __restrict__ value,
                           float* __restrict__ part) {
    const int tc = blockIdx.x;   // 16
    const int hc = blockIdx.y;   // 2
    const int b  = blockIdx.z;   // 32
    const int tid = threadIdx.x; // 128
    __shared__ float sw[128];
    sw[tid] = w[(long)b * TSEQ + tc * 128 + tid];
    __syncthreads();
    const int h = hc * 512 + tid * 4;
    float4 acc = {0.f, 0.f, 0.f, 0.f};
    const float* vbase = value + ((long)b * TSEQ + tc * 128) * HDIM + h;
#pragma unroll 4
    for (int tt = 0; tt < 128; ++tt) {
        float4 v = *(const float4*)(vbase + (long)tt * HDIM);
        float wv = sw[tt];
        acc.x += wv * v.x; acc.y += wv * v.y;
        acc.z += wv * v.z; acc.w += wv * v.w;
    }
    *(float4*)(part + ((long)(b * 16 + tc)) * HDIM + h) = acc;
}

__global__ void pv_reduce(const float* __restrict__ part, float* __restrict__ out) {
    const int b = blockIdx.x;    // 32
    const int tid = threadIdx.x; // 256
    const int h = tid * 4;
    float4 acc = {0.f, 0.f, 0.f, 0.f};
#pragma unroll
    for (int tc = 0; tc < 16; ++tc) {
        float4 v = *(const float4*)(part + ((long)(b * 16 + tc)) * HDIM + h);
        acc.x += v.x; acc.y += v.y; acc.z += v.z; acc.w += v.w;
    }
    *(float4*)(out + (long)b * HDIM + h) = acc;
}

extern "C" void kernel_launch(void* const* d_in, const int* in_sizes, int n_in,
                              void* d_out, int out_size, void* d_ws, size_t ws_size,
                              hipStream_t stream) {
    const float* query   = (const float*)d_in[0];
    const float* key_    = (const float*)d_in[1];
    const float* value   = (const float*)d_in[2];
    const int*   lengths = (const int*)d_in[3];
    const float* Wq = (const float*)d_in[4];
    const float* bq = (const float*)d_in[5];
    const float* Wk = (const float*)d_in[6];
    const float* bk = (const float*)d_in[7];
    const float* Wz = (const float*)d_in[8];
    const float* bz = (const float*)d_in[9];
    float* out = (float*)d_out;

    float* sp   = (float*)d_ws;                              // 65536*16 f32 = 4 MB
    float* wbuf = sp + (long)65536 * NPART;                  // 65536 f32
    float* p2   = wbuf + 65536;                              // 32*16*1024 f32 = 2 MB

    const int mblocks = (BATCH * TSEQ) / BM;  // 512
    const int nblocks = HDIM / BN;            // 8
    score_gemm<<<dim3(mblocks * nblocks), dim3(256), 0, stream>>>(
        query, key_, Wq, Wk, bq, bk, Wz, sp);
    softmax_kernel<<<dim3(BATCH), dim3(256), 0, stream>>>(
        sp, bz, lengths, out + BATCH * HDIM, wbuf);
    pv_partial<<<dim3(16, 2, BATCH), dim3(128), 0, stream>>>(wbuf, value, p2);
    pv_reduce<<<dim3(BATCH), dim3(256), 0, stream>>>(p2, out);
}